// Round 24
// baseline (128.617 us; speedup 1.0000x reference)
//
#include <hip/hip_runtime.h>
#include <hip/hip_bf16.h>
#include <math.h>

#define N_ATOMS 10000
#define N_PAIRS 160000
#define FDIM 256
#define GDIM 16
#define HDIM 64
#define HIDDIM 256
#define MLP_IN 640
#define MLP_OUT 258
#define KB1 11   // MLP phase-1 K-blocks: K = 352 = 256 emb + 64 vec + 16 qGs + 16 pad

typedef __attribute__((ext_vector_type(8))) short short8;
typedef __attribute__((ext_vector_type(4))) unsigned short u16x4;
typedef __attribute__((ext_vector_type(4))) float f32x4;

#define MFMA16(a, b, c) __builtin_amdgcn_mfma_f32_16x16x32_bf16((a), (b), (c), 0, 0, 0)

// MFMA-native tiled layout for bf16 operand X[N][K]:
//   Xt[nb][kb][kg][nr][ke],  nb=N/16, kb=K/32, kg=4, nr=16, ke=8
//   flat = (nb*KB + kb)*512 + lane*8
// so a wave's 16x32 fragment load is ONE contiguous 1KB transaction.

__device__ __forceinline__ float gelu_exact(float x) {
    return 0.5f * x * (1.0f + erff(x * 0.70710678118654752f));
}
__device__ __forceinline__ short bf16bits(float x) {
    __hip_bfloat16 h = __float2bfloat16(x);
    return *reinterpret_cast<short*>(&h);
}
__device__ __forceinline__ float bf2f(unsigned short u) {
    return __uint_as_float(((unsigned)u) << 16);
}
__device__ __forceinline__ short8 cvt8(f32x4 v0, f32x4 v1) {
    short8 o;
    o[0] = bf16bits(v0[0]); o[1] = bf16bits(v0[1]);
    o[2] = bf16bits(v0[2]); o[3] = bf16bits(v0[3]);
    o[4] = bf16bits(v1[0]); o[5] = bf16bits(v1[1]);
    o[6] = bf16bits(v1[2]); o[7] = bf16bits(v1[3]);
    return o;
}

// ---------------------------------------------------------------------------
// Prep: weights into MFMA-native layout. W1t (KB=11): cols 0..319 from W1,
// cols 320..335 = V1 = W1[:,320:576] @ W_gs (rank-16 collapse of radial_q,
// exact algebra), cols 336..351 = 0. Plus W2t, aghTt, W3t, cnt.
// ---------------------------------------------------------------------------
#define PV_W1M 10240   // 256 rows x 40 octets (k < 320)
#define PV_V1  4096    // 256 rows x 16 g  (each: 256-FMA dot)
#define PV_W1Z 512     // 256 rows x 2 zero octets (k 336..351)
#define PV_W2  8192
#define PV_AGH 32768
#define PV_W3  10240
#define PV_CNT 10000
#define PREP_TOTAL (PV_W1M + PV_V1 + PV_W1Z + PV_W2 + PV_AGH + PV_W3 + PV_CNT)
__global__ void prep_kernel(const float* __restrict__ W1,
                            const float* __restrict__ W_gs,
                            const float* __restrict__ W2,
                            const float* __restrict__ agh,
                            const float* __restrict__ W3,
                            short* __restrict__ W1t,
                            short* __restrict__ W2t,
                            short* __restrict__ aghTt,
                            short* __restrict__ W3t,
                            int* __restrict__ cnt) {
    int tid = blockIdx.x * blockDim.x + threadIdx.x;
    if (tid >= PREP_TOTAL) return;
    int j = tid;
    if (j < PV_W1M) {   // W1 direct part: k-octets 0..39
        int n = j / 40, k8 = j % 40;
        int dst = (((n >> 4) * KB1 + (k8 >> 2)) * 4 + (k8 & 3)) * 128 + (n & 15) * 8;
        const float* src = W1 + n * 640 + k8 * 8;
        *(short8*)(W1t + dst) = cvt8(*(const f32x4*)src, *(const f32x4*)(src + 4));
        return;
    }
    j -= PV_W1M;
    if (j < PV_V1) {    // V1[n][g] = sum_f W1[n][320+f] * W_gs[f][g]
        int n = j >> 4, g = j & 15;
        const float* wrow = W1 + n * 640 + 320;
        float acc = 0.f;
#pragma unroll 8
        for (int f = 0; f < 256; ++f)
            acc += wrow[f] * W_gs[f * 16 + g];
        int dst = (((n >> 4) * KB1 + 10) * 4 + (g >> 3)) * 128 + (n & 15) * 8 + (g & 7);
        W1t[dst] = bf16bits(acc);
        return;
    }
    j -= PV_V1;
    if (j < PV_W1Z) {   // zero pad: k-octets 42,43 (k 336..351)
        int n = j >> 1, oct = j & 1;
        int dst = (((n >> 4) * KB1 + 10) * 4 + (2 + oct)) * 128 + (n & 15) * 8;
        short8 z = {};
        *(short8*)(W1t + dst) = z;
        return;
    }
    j -= PV_W1Z;
    if (j < PV_W2) {
        int n = j >> 5, k8 = j & 31;
        int dst = (((n >> 4) * 8 + (k8 >> 2)) * 4 + (k8 & 3)) * 128 + (n & 15) * 8;
        const float* src = W2 + n * 256 + k8 * 8;
        *(short8*)(W2t + dst) = cvt8(*(const f32x4*)src, *(const f32x4*)(src + 4));
        return;
    }
    j -= PV_W2;
    if (j < PV_AGH) {  // agh[k][n] (k=f, n=g*64+h) -> native layout
        int n = j >> 5, k8 = j & 31;
        int k0 = k8 * 8;
        short8 o;
#pragma unroll
        for (int i = 0; i < 8; ++i)
            o[i] = bf16bits(agh[(long long)(k0 + i) * 1024 + n]);
        int dst = (((n >> 4) * 8 + (k8 >> 2)) * 4 + (k8 & 3)) * 128 + (n & 15) * 8;
        *(short8*)(aghTt + dst) = o;
        return;
    }
    j -= PV_AGH;
    if (j < PV_W3) {   // rows n>=258 zero
        int n = j >> 5, k8 = j & 31;
        int dst = (((n >> 4) * 8 + (k8 >> 2)) * 4 + (k8 & 3)) * 128 + (n & 15) * 8;
        if (n < MLP_OUT) {
            const float* src = W3 + n * 256 + k8 * 8;
            *(short8*)(W3t + dst) = cvt8(*(const f32x4*)src, *(const f32x4*)(src + 4));
        } else {
            short8 z = {};
            *(short8*)(W3t + dst) = z;
        }
        return;
    }
    j -= PV_W3;
    cnt[j] = 0;
}

// ---------------------------------------------------------------------------
// Count-sort: hist -> scan -> scatter_data (sort-ordered bf16 pair rows).
// ---------------------------------------------------------------------------
__global__ void hist_kernel(const int* __restrict__ idx_j, int* __restrict__ cnt) {
    int p = blockIdx.x * blockDim.x + threadIdx.x;
    if (p >= N_PAIRS) return;
    atomicAdd(&cnt[idx_j[p]], 1);
}

__global__ __launch_bounds__(1024) void scan_kernel(const int* __restrict__ cnt,
                                                    int* __restrict__ start,
                                                    int* __restrict__ cursor) {
    __shared__ int part[1024];
    int t = threadIdx.x;
    int base = t * 10;
    int pre[10];
    int sum = 0;
#pragma unroll
    for (int k = 0; k < 10; ++k) {
        int i = base + k;
        int v = (i < N_ATOMS) ? cnt[i] : 0;
        pre[k] = sum;
        sum += v;
    }
    part[t] = sum;
    __syncthreads();
    for (int off = 1; off < 1024; off <<= 1) {
        int v = (t >= off) ? part[t - off] : 0;
        __syncthreads();
        part[t] += v;
        __syncthreads();
    }
    int excl = (t == 0) ? 0 : part[t - 1];
#pragma unroll
    for (int k = 0; k < 10; ++k) {
        int i = base + k;
        if (i < N_ATOMS) {
            start[i]  = excl + pre[k];
            cursor[i] = excl + pre[k];
        }
    }
}

__global__ void scatter_data_kernel(const int* __restrict__ idx_j,
                                    int* __restrict__ cursor,
                                    const float* __restrict__ gs,
                                    const float* __restrict__ gv,
                                    __hip_bfloat16* __restrict__ prS) {
    int p = blockIdx.x * blockDim.x + threadIdx.x;
    if (p >= N_PAIRS) return;
    int i = idx_j[p];
    int pos = atomicAdd(&cursor[i], 1);
    short* dst = (short*)prS + (long long)pos * 64;
    const float* g1 = gs + (long long)p * 16;
    *(short8*)(dst)     = cvt8(*(const f32x4*)(g1),     *(const f32x4*)(g1 + 4));
    *(short8*)(dst + 8) = cvt8(*(const f32x4*)(g1 + 8), *(const f32x4*)(g1 + 12));
    const float* g2 = gv + (long long)p * 48;
#pragma unroll
    for (int k = 0; k < 6; ++k)
        *(short8*)(dst + 16 + k * 8) =
            cvt8(*(const f32x4*)(g2 + k * 8), *(const f32x4*)(g2 + k * 8 + 4));
}

// ---------------------------------------------------------------------------
// gatherM_build: r17-proven phases A/C; phase B writes emb part (k=t) +
// 16-col qGs part (k=320+g) + 16-col zero pad (k=336+g). comb_t KB=11.
// 16 atoms/block, grid 625.
// ---------------------------------------------------------------------------
__global__ __launch_bounds__(256) void gatherM_build(
        const __hip_bfloat16* __restrict__ prS,
        const int* __restrict__ start,
        const int* __restrict__ cnt,
        const float* __restrict__ emb,
        const float* __restrict__ q,
        const float* __restrict__ W_gs,
        const short* __restrict__ aghTt,
        short* __restrict__ comb_t) {
    __shared__ float sW[FDIM * 17];
    __shared__ short sE[16][264];
    __shared__ float sG[16][GDIM];
    __shared__ float sGV[16][48];
    int i0 = blockIdx.x * 16;
    int mb = blockIdx.x;
    int t = threadIdx.x;

    for (int j = t; j < FDIM * GDIM; j += 256)
        sW[(j >> 4) * 17 + (j & 15)] = W_gs[j];

    {   // stage emb rows -> bf16 LDS (16 elems/thread, vectorized)
        int r = t >> 4, cb = (t & 15) * 16;
        const float* src = emb + (long long)(i0 + r) * FDIM + cb;
        *(short8*)(&sE[r][cb])     = cvt8(*(const f32x4*)(src),     *(const f32x4*)(src + 4));
        *(short8*)(&sE[r][cb + 8]) = cvt8(*(const f32x4*)(src + 8), *(const f32x4*)(src + 12));
    }

    // Phase A (r17-proven): streaming gather, 16 lanes/atom, 8B/lane
    {
        int grp = t >> 4, l = t & 15;
        int atom = i0 + grp;
        int s = start[atom], c = cnt[atom];
        const unsigned short* base = (const unsigned short*)prS + (long long)s * 64 + l * 4;
        f32x4 acc = {0.f, 0.f, 0.f, 0.f};
        int j = 0;
        for (; j + 1 < c; j += 2) {
            u16x4 v0 = *(const u16x4*)(base + (long long)j * 64);
            u16x4 v1 = *(const u16x4*)(base + (long long)(j + 1) * 64);
            acc[0] += bf2f(v0[0]) + bf2f(v1[0]);
            acc[1] += bf2f(v0[1]) + bf2f(v1[1]);
            acc[2] += bf2f(v0[2]) + bf2f(v1[2]);
            acc[3] += bf2f(v0[3]) + bf2f(v1[3]);
        }
        if (j < c) {
            u16x4 v0 = *(const u16x4*)(base + (long long)j * 64);
            acc[0] += bf2f(v0[0]);
            acc[1] += bf2f(v0[1]);
            acc[2] += bf2f(v0[2]);
            acc[3] += bf2f(v0[3]);
        }
        if (l < 4) *(f32x4*)&sG[grp][l * 4] = acc;
        else       *(f32x4*)&sGV[grp][(l - 4) * 4] = acc;
    }
    __syncthreads();

    // Phase B: radial_emb (k=t, all 16 atoms) + qGs (k=320+g) + pad (k=336+g)
    {
        float wreg[GDIM];
#pragma unroll
        for (int g = 0; g < GDIM; ++g) wreg[g] = sW[t * 17 + g];
        int kb1 = t >> 5, kg1 = (t >> 3) & 3, ke1 = t & 7;
        long long b1f = (((long long)mb * KB1 + kb1) * 4 + kg1) * 128 + ke1;
#pragma unroll 4
        for (int a = 0; a < 16; ++a) {
            int i = i0 + a;
            float S = 0.f;
#pragma unroll
            for (int g = 0; g < GDIM; ++g) S += sG[a][g] * wreg[g];
            float ev = emb[(long long)i * FDIM + t];
            comb_t[b1f + a * 8] = bf16bits(ev * S);
        }
        // qGs + pad: thread t -> (atom a = t>>4, g = t&15)
        int a = t >> 4, g = t & 15;
        float val = q[i0 + a] * sG[a][g];
        long long oq = (((long long)mb * KB1 + 10) * 4 + (g >> 3)) * 128 + a * 8 + (g & 7);
        long long oz = (((long long)mb * KB1 + 10) * 4 + 2 + (g >> 3)) * 128 + a * 8 + (g & 7);
        comb_t[oq] = bf16bits(val);
        comb_t[oz] = bf16bits(0.f);
    }

    // Phase C (r17-proven): fused M-contraction + vector_emb (k = 256+wave*16+lr)
    {
        int lane = t & 63, wave = t >> 6;
        int lr = lane & 15;
        int ko = (lane >> 4) * 8;
        int rbase = (lane >> 4) * 4;

        short8 af[8];
#pragma unroll
        for (int ks = 0; ks < 8; ++ks)
            af[ks] = *(const short8*)(&sE[lr][ks * 32 + ko]);

        float U0[4] = {}, U1[4] = {}, U2[4] = {};
#pragma unroll
        for (int g = 0; g < 16; ++g) {
            f32x4 acc = {0.f, 0.f, 0.f, 0.f};
            int nb = g * 4 + wave;   // n = g*64 + wave*16
            const short* Bb = aghTt + (long long)nb * 8 * 512 + lane * 8;
#pragma unroll
            for (int kb = 0; kb < 8; ++kb) {
                short8 b = *(const short8*)(Bb + kb * 512);
                acc = MFMA16(af[kb], b, acc);
            }
#pragma unroll
            for (int r = 0; r < 4; ++r) {
                int a = rbase + r;
                U0[r] += acc[r] * sGV[a][g];
                U1[r] += acc[r] * sGV[a][16 + g];
                U2[r] += acc[r] * sGV[a][32 + g];
            }
        }
        int off = wave * 16 + lr;           // k = 256 + off
        int kb = 8 + (off >> 5), kg = (off >> 3) & 3, ke = off & 7;
        long long bf = (((long long)mb * KB1 + kb) * 4 + kg) * 128 + ke;
#pragma unroll
        for (int r = 0; r < 4; ++r) {
            int a = rbase + r;
            float v = sqrtf(U0[r] * U0[r] + U1[r] * U1[r] + U2[r] * U2[r]);
            comb_t[bf + a * 8] = bf16bits(v);
        }
    }
}

// ---------------------------------------------------------------------------
// Fused MLP (r17-proven structure): 32 atoms per 512-thr block, grid 313.
// Phase 1 KB=11 (K=352 via V1 collapse). Phases 2/3 unchanged.
// ---------------------------------------------------------------------------
__global__ __launch_bounds__(512) void mlp_fused(
        const short* __restrict__ comb_t,
        const short* __restrict__ W1t,
        const short* __restrict__ W2t,
        const short* __restrict__ W3t,
        const float* __restrict__ b1,
        const float* __restrict__ b2,
        const float* __restrict__ b3,
        float* __restrict__ outp) {
    __shared__ short h1s[32][264];
    __shared__ short h2s[32][264];
    int lane = threadIdx.x & 63;
    int wave = threadIdx.x >> 6;
    int m0 = blockIdx.x * 32;
    int mbb = blockIdx.x * 2;
    int lr = lane & 15;
    int ko = (lane >> 4) * 8;
    int rbase = (lane >> 4) * 4;

    const short* At[2];
#pragma unroll
    for (int fm = 0; fm < 2; ++fm) {
        int mb = mbb + fm;
        if (mb > 624) mb = 624;   // clamp; garbage rows discarded at store
        At[fm] = comb_t + (long long)mb * KB1 * 512 + lane * 8;
    }

    // Phase 1: h1 = gelu(comb @ W1'^T + b1); wave cols [32w, 32w+32), KB=11
    {
        f32x4 acc[2][2] = {};
        const short* Bt = W1t + (long long)(wave * 2) * KB1 * 512 + lane * 8;
#pragma unroll 3
        for (int kbi = 0; kbi < KB1; ++kbi) {
            short8 a[2], b[2];
#pragma unroll
            for (int fm = 0; fm < 2; ++fm) a[fm] = *(const short8*)(At[fm] + kbi * 512);
#pragma unroll
            for (int fn = 0; fn < 2; ++fn)
                b[fn] = *(const short8*)(Bt + fn * KB1 * 512 + kbi * 512);
#pragma unroll
            for (int fm = 0; fm < 2; ++fm)
#pragma unroll
                for (int fn = 0; fn < 2; ++fn)
                    acc[fm][fn] = MFMA16(a[fm], b[fn], acc[fm][fn]);
        }
#pragma unroll
        for (int fn = 0; fn < 2; ++fn) {
            int col = wave * 32 + fn * 16 + lr;
            float bias = b1[col];
#pragma unroll
            for (int fm = 0; fm < 2; ++fm)
#pragma unroll
                for (int r = 0; r < 4; ++r)
                    h1s[fm * 16 + rbase + r][col] = bf16bits(gelu_exact(acc[fm][fn][r] + bias));
        }
    }
    __syncthreads();

    // Phase 2: h2 = gelu(h1 @ W2^T + b2); A from LDS, B native (KB=8)
    {
        f32x4 acc[2][2] = {};
        const short* Bt = W2t + (long long)(wave * 2) * 8 * 512 + lane * 8;
#pragma unroll
        for (int kbi = 0; kbi < 8; ++kbi) {
            short8 a[2], b[2];
#pragma unroll
            for (int fm = 0; fm < 2; ++fm)
                a[fm] = *(const short8*)(&h1s[fm * 16 + lr][ko + kbi * 32]);
#pragma unroll
            for (int fn = 0; fn < 2; ++fn)
                b[fn] = *(const short8*)(Bt + fn * 8 * 512 + kbi * 512);
#pragma unroll
            for (int fm = 0; fm < 2; ++fm)
#pragma unroll
                for (int fn = 0; fn < 2; ++fn)
                    acc[fm][fn] = MFMA16(a[fm], b[fn], acc[fm][fn]);
        }
#pragma unroll
        for (int fn = 0; fn < 2; ++fn) {
            int col = wave * 32 + fn * 16 + lr;
            float bias = b2[col];
#pragma unroll
            for (int fm = 0; fm < 2; ++fm)
#pragma unroll
                for (int r = 0; r < 4; ++r)
                    h2s[fm * 16 + rbase + r][col] = bf16bits(gelu_exact(acc[fm][fn][r] + bias));
        }
    }
    __syncthreads();

    // Phase 3: out = h2 @ W3^T + b3 (320 padded cols = 20 frags, KB=8)
    {
        int f0 = wave, f1 = wave + 8, f2 = wave + 16;
        bool has2 = (wave < 4);
        f32x4 acc0[2] = {}, acc1[2] = {}, acc2[2] = {};
        const short* B0 = W3t + (long long)f0 * 8 * 512 + lane * 8;
        const short* B1 = W3t + (long long)f1 * 8 * 512 + lane * 8;
        const short* B2 = W3t + (long long)(has2 ? f2 : f0) * 8 * 512 + lane * 8;
#pragma unroll
        for (int kbi = 0; kbi < 8; ++kbi) {
            short8 a[2];
#pragma unroll
            for (int fm = 0; fm < 2; ++fm)
                a[fm] = *(const short8*)(&h2s[fm * 16 + lr][ko + kbi * 32]);
            short8 b0 = *(const short8*)(B0 + kbi * 512);
            short8 b1v = *(const short8*)(B1 + kbi * 512);
#pragma unroll
            for (int fm = 0; fm < 2; ++fm) {
                acc0[fm] = MFMA16(a[fm], b0, acc0[fm]);
                acc1[fm] = MFMA16(a[fm], b1v, acc1[fm]);
            }
            if (has2) {
                short8 b2v = *(const short8*)(B2 + kbi * 512);
#pragma unroll
                for (int fm = 0; fm < 2; ++fm)
                    acc2[fm] = MFMA16(a[fm], b2v, acc2[fm]);
            }
        }
#pragma unroll
        for (int slot = 0; slot < 3; ++slot) {
            if (slot == 2 && !has2) continue;
            int f = (slot == 0) ? f0 : (slot == 1) ? f1 : f2;
            int col = f * 16 + lr;
            if (col >= MLP_OUT) continue;
            float bias = b3[col];
#pragma unroll
            for (int fm = 0; fm < 2; ++fm) {
#pragma unroll
                for (int r = 0; r < 4; ++r) {
                    int row = m0 + fm * 16 + rbase + r;
                    if (row >= N_ATOMS) continue;
                    f32x4 av = (slot == 0) ? acc0[fm] : (slot == 1) ? acc1[fm] : acc2[fm];
                    float v = av[r] + bias;
                    if (col == 0)      outp[2560000 + row] = v;
                    else if (col == 1) outp[2570000 + row] = v;
                    else               outp[(long long)row * 256 + (col - 2)] = v;
                }
            }
        }
    }
}

extern "C" void kernel_launch(void* const* d_in, const int* in_sizes, int n_in,
                              void* d_out, int out_size, void* d_ws, size_t ws_size,
                              hipStream_t stream) {
    const float* emb  = (const float*)d_in[0];
    const float* q    = (const float*)d_in[1];
    const int*   pidx = (const int*)d_in[2];
    const float* gs   = (const float*)d_in[3];
    const float* gv   = (const float*)d_in[4];
    const float* agh  = (const float*)d_in[5];
    const float* W_gs = (const float*)d_in[6];
    const float* W1   = (const float*)d_in[7];
    const float* b1   = (const float*)d_in[8];
    const float* W2   = (const float*)d_in[9];
    const float* b2   = (const float*)d_in[10];
    const float* W3   = (const float*)d_in[11];
    const float* b3   = (const float*)d_in[12];
    float* out = (float*)d_out;
    float* ws  = (float*)d_ws;

    // Workspace (float-slot offsets). Peak 7,159,856 floats = 28.6 MB
    // (42.9 MB proven safe in r5).
    int*   cnt    = (int*)(ws);                       // 10,000
    int*   startA = (int*)(ws + 10000);               // 10,000
    int*   cursor = (int*)(ws + 20000);               // 10,000
    __hip_bfloat16* prS = (__hip_bfloat16*)(ws + 30000);  // 160000x64 bf16 (5,120,000 f)
    short* aghTt = (short*)(ws + 5150000);            // 262,144 elems (131,072 f)
    short* W1t   = (short*)(ws + 5281072);            // 16*11*512 = 90,112 elems (45,056 f)
    short* W2t   = (short*)(ws + 5326128);            // 65,536 elems (32,768 f)
    short* W3t   = (short*)(ws + 5358896);            // 81,920 elems (40,960 f)
    short* comb_t= (short*)(ws + 5399856);            // 625*11*512 = 3,520,000 elems (1,760,000 f)
    // end: 7,159,856 floats

    const int* idx_j = pidx + N_PAIRS;

    {   // weight conversions (incl. V1 collapse) + cnt zeroing
        int blocks = (PREP_TOTAL + 255) / 256;
        prep_kernel<<<blocks, 256, 0, stream>>>(W1, W_gs, W2, agh, W3,
                                                W1t, W2t, aghTt, W3t, cnt);
    }
    {   // count-sort pairs by atom + materialize sort-ordered bf16 pair rows
        int blocks = (N_PAIRS + 255) / 256;
        hist_kernel<<<blocks, 256, 0, stream>>>(idx_j, cnt);
        scan_kernel<<<1, 1024, 0, stream>>>(cnt, startA, cursor);
        scatter_data_kernel<<<blocks, 256, 0, stream>>>(idx_j, cursor, gs, gv, prS);
    }
    // streaming gather + M-contraction + combined-builder (625 blocks)
    gatherM_build<<<625, 256, 0, stream>>>(
        prS, startA, cnt, emb, q, W_gs, aghTt, comb_t);
    // fused 3-layer MLP + output remap (313 blocks x 512 thr)
    mlp_fused<<<(N_ATOMS + 31) / 32, 512, 0, stream>>>(
        comb_t, W1t, W2t, W3t, b1, b2, b3, out);
}

// Round 27
// 103.998 us; speedup vs baseline: 1.2367x; 1.2367x over previous
//
#include <hip/hip_runtime.h>
#include <hip/hip_bf16.h>
#include <math.h>

#define N_ATOMS 10000
#define N_PAIRS 160000
#define FDIM 256
#define GDIM 16
#define HDIM 64
#define HIDDIM 256
#define MLP_IN 640
#define MLP_OUT 258

typedef __attribute__((ext_vector_type(8))) short short8;
typedef __attribute__((ext_vector_type(4))) unsigned short u16x4;
typedef __attribute__((ext_vector_type(4))) float f32x4;

#define MFMA16(a, b, c) __builtin_amdgcn_mfma_f32_16x16x32_bf16((a), (b), (c), 0, 0, 0)

// MFMA-native tiled layout for bf16 operand X[N][K]:
//   Xt[nb][kb][kg][nr][ke],  nb=N/16, kb=K/32, kg=4, nr=16, ke=8
//   flat = (nb*KB + kb)*512 + lane*8
// so a wave's 16x32 fragment load is ONE contiguous 1KB transaction.

__device__ __forceinline__ float gelu_exact(float x) {
    return 0.5f * x * (1.0f + erff(x * 0.70710678118654752f));
}
__device__ __forceinline__ short bf16bits(float x) {
    __hip_bfloat16 h = __float2bfloat16(x);
    return *reinterpret_cast<short*>(&h);
}
__device__ __forceinline__ float bf2f(unsigned short u) {
    return __uint_as_float(((unsigned)u) << 16);
}
__device__ __forceinline__ short8 cvt8(f32x4 v0, f32x4 v1) {
    short8 o;
    o[0] = bf16bits(v0[0]); o[1] = bf16bits(v0[1]);
    o[2] = bf16bits(v0[2]); o[3] = bf16bits(v0[3]);
    o[4] = bf16bits(v1[0]); o[5] = bf16bits(v1[1]);
    o[6] = bf16bits(v1[2]); o[7] = bf16bits(v1[3]);
    return o;
}

// ---------------------------------------------------------------------------
// Prep: weights + aghT into MFMA-native layout (vectorized, 8 elems/thread).
// ---------------------------------------------------------------------------
#define PV_W1  18432   // 256*72
#define PV_W2  8192    // 256*32
#define PV_AGH 32768   // 1024*32
#define PV_W3  10240   // 320*32
#define PV_CNT 10000
#define PREP_TOTAL (PV_W1 + PV_W2 + PV_AGH + PV_W3 + PV_CNT)
__global__ void prep_kernel(const float* __restrict__ W1,
                            const float* __restrict__ W2,
                            const float* __restrict__ agh,
                            const float* __restrict__ W3,
                            short* __restrict__ W1t,
                            short* __restrict__ W2t,
                            short* __restrict__ aghTt,
                            short* __restrict__ W3t,
                            int* __restrict__ cnt) {
    int tid = blockIdx.x * blockDim.x + threadIdx.x;
    if (tid >= PREP_TOTAL) return;
    int j = tid;
    if (j < PV_W1) {   // K=576 -> 72 k-octets per row
        int n = j / 72, k8 = j % 72;
        int dst = (((n >> 4) * 18 + (k8 >> 2)) * 4 + (k8 & 3)) * 128 + (n & 15) * 8;
        const float* src = W1 + n * 640 + k8 * 8;
        *(short8*)(W1t + dst) = cvt8(*(const f32x4*)src, *(const f32x4*)(src + 4));
        return;
    }
    j -= PV_W1;
    if (j < PV_W2) {
        int n = j >> 5, k8 = j & 31;
        int dst = (((n >> 4) * 8 + (k8 >> 2)) * 4 + (k8 & 3)) * 128 + (n & 15) * 8;
        const float* src = W2 + n * 256 + k8 * 8;
        *(short8*)(W2t + dst) = cvt8(*(const f32x4*)src, *(const f32x4*)(src + 4));
        return;
    }
    j -= PV_W2;
    if (j < PV_AGH) {  // agh[k][n] (k=f, n=g*64+h) -> native [nb][kb][kg][nr][ke]
        int n = j >> 5, k8 = j & 31;
        int k0 = k8 * 8;
        short8 o;
#pragma unroll
        for (int i = 0; i < 8; ++i)
            o[i] = bf16bits(agh[(long long)(k0 + i) * 1024 + n]);
        int dst = (((n >> 4) * 8 + (k8 >> 2)) * 4 + (k8 & 3)) * 128 + (n & 15) * 8;
        *(short8*)(aghTt + dst) = o;
        return;
    }
    j -= PV_AGH;
    if (j < PV_W3) {   // rows n>=258 zero
        int n = j >> 5, k8 = j & 31;
        int dst = (((n >> 4) * 8 + (k8 >> 2)) * 4 + (k8 & 3)) * 128 + (n & 15) * 8;
        if (n < MLP_OUT) {
            const float* src = W3 + n * 256 + k8 * 8;
            *(short8*)(W3t + dst) = cvt8(*(const f32x4*)src, *(const f32x4*)(src + 4));
        } else {
            short8 z = {};
            *(short8*)(W3t + dst) = z;
        }
        return;
    }
    j -= PV_W3;
    cnt[j] = 0;
}

// ---------------------------------------------------------------------------
// Count-sort: hist -> scan -> scatter_data (sort-ordered bf16 pair rows,
// random WRITES / streaming reads).
// ---------------------------------------------------------------------------
__global__ void hist_kernel(const int* __restrict__ idx_j, int* __restrict__ cnt) {
    int p = blockIdx.x * blockDim.x + threadIdx.x;
    if (p >= N_PAIRS) return;
    atomicAdd(&cnt[idx_j[p]], 1);
}

__global__ __launch_bounds__(1024) void scan_kernel(const int* __restrict__ cnt,
                                                    int* __restrict__ start,
                                                    int* __restrict__ cursor) {
    __shared__ int part[1024];
    int t = threadIdx.x;
    int base = t * 10;
    int pre[10];
    int sum = 0;
#pragma unroll
    for (int k = 0; k < 10; ++k) {
        int i = base + k;
        int v = (i < N_ATOMS) ? cnt[i] : 0;
        pre[k] = sum;
        sum += v;
    }
    part[t] = sum;
    __syncthreads();
    for (int off = 1; off < 1024; off <<= 1) {
        int v = (t >= off) ? part[t - off] : 0;
        __syncthreads();
        part[t] += v;
        __syncthreads();
    }
    int excl = (t == 0) ? 0 : part[t - 1];
#pragma unroll
    for (int k = 0; k < 10; ++k) {
        int i = base + k;
        if (i < N_ATOMS) {
            start[i]  = excl + pre[k];
            cursor[i] = excl + pre[k];
        }
    }
}

__global__ void scatter_data_kernel(const int* __restrict__ idx_j,
                                    int* __restrict__ cursor,
                                    const float* __restrict__ gs,
                                    const float* __restrict__ gv,
                                    __hip_bfloat16* __restrict__ prS) {
    int p = blockIdx.x * blockDim.x + threadIdx.x;
    if (p >= N_PAIRS) return;
    int i = idx_j[p];
    int pos = atomicAdd(&cursor[i], 1);
    short* dst = (short*)prS + (long long)pos * 64;
    const float* g1 = gs + (long long)p * 16;
    *(short8*)(dst)     = cvt8(*(const f32x4*)(g1),     *(const f32x4*)(g1 + 4));
    *(short8*)(dst + 8) = cvt8(*(const f32x4*)(g1 + 8), *(const f32x4*)(g1 + 12));
    const float* g2 = gv + (long long)p * 48;
#pragma unroll
    for (int k = 0; k < 6; ++k)
        *(short8*)(dst + 16 + k * 8) =
            cvt8(*(const f32x4*)(g2 + k * 8), *(const f32x4*)(g2 + k * 8 + 4));
}

// ---------------------------------------------------------------------------
// gatherM_build: streaming gather over prS + fused emb@agh contraction (MFMA,
// native-layout aghT) + combined-row construction into comb_t (native layout,
// MB=625, KB=18). 16 atoms/block, grid 625.
// ---------------------------------------------------------------------------
__global__ __launch_bounds__(256) void gatherM_build(
        const __hip_bfloat16* __restrict__ prS,
        const int* __restrict__ start,
        const int* __restrict__ cnt,
        const float* __restrict__ emb,
        const float* __restrict__ q,
        const float* __restrict__ W_gs,
        const short* __restrict__ aghTt,
        short* __restrict__ comb_t) {
    __shared__ float sW[FDIM * 17];
    __shared__ short sE[16][264];
    __shared__ float sG[16][GDIM];
    __shared__ float sGV[16][48];
    int i0 = blockIdx.x * 16;
    int mb = blockIdx.x;
    int t = threadIdx.x;

    for (int j = t; j < FDIM * GDIM; j += 256)
        sW[(j >> 4) * 17 + (j & 15)] = W_gs[j];

    {   // stage emb rows -> bf16 LDS (16 elems/thread, vectorized)
        int r = t >> 4, cb = (t & 15) * 16;
        const float* src = emb + (long long)(i0 + r) * FDIM + cb;
        *(short8*)(&sE[r][cb])     = cvt8(*(const f32x4*)(src),     *(const f32x4*)(src + 4));
        *(short8*)(&sE[r][cb + 8]) = cvt8(*(const f32x4*)(src + 8), *(const f32x4*)(src + 12));
    }

    // Phase A: streaming gather (16 lanes per atom, 8B/lane, rows contiguous)
    {
        int grp = t >> 4, l = t & 15;
        int atom = i0 + grp;
        int s = start[atom], c = cnt[atom];
        const unsigned short* base = (const unsigned short*)prS + (long long)s * 64 + l * 4;
        f32x4 acc = {0.f, 0.f, 0.f, 0.f};
        int j = 0;
        for (; j + 1 < c; j += 2) {
            u16x4 v0 = *(const u16x4*)(base + (long long)j * 64);
            u16x4 v1 = *(const u16x4*)(base + (long long)(j + 1) * 64);
            acc[0] += bf2f(v0[0]) + bf2f(v1[0]);
            acc[1] += bf2f(v0[1]) + bf2f(v1[1]);
            acc[2] += bf2f(v0[2]) + bf2f(v1[2]);
            acc[3] += bf2f(v0[3]) + bf2f(v1[3]);
        }
        if (j < c) {
            u16x4 v0 = *(const u16x4*)(base + (long long)j * 64);
            acc[0] += bf2f(v0[0]);
            acc[1] += bf2f(v0[1]);
            acc[2] += bf2f(v0[2]);
            acc[3] += bf2f(v0[3]);
        }
        if (l < 4) *(f32x4*)&sG[grp][l * 4] = acc;
        else       *(f32x4*)&sGV[grp][(l - 4) * 4] = acc;
    }
    __syncthreads();

    // Phase B: radial_emb (k=t) / radial_q (k=320+t) into comb_t
    {
        float wreg[GDIM];
#pragma unroll
        for (int g = 0; g < GDIM; ++g) wreg[g] = sW[t * 17 + g];
        int kb1 = t >> 5, kg1 = (t >> 3) & 3, ke1 = t & 7;
        int k2 = 320 + t;
        int kb2 = k2 >> 5, kg2 = (k2 >> 3) & 3, ke2 = k2 & 7;
        long long b1f = (((long long)mb * 18 + kb1) * 4 + kg1) * 128 + ke1;
        long long b2f = (((long long)mb * 18 + kb2) * 4 + kg2) * 128 + ke2;
#pragma unroll 4
        for (int a = 0; a < 16; ++a) {
            int i = i0 + a;
            float S = 0.f;
#pragma unroll
            for (int g = 0; g < GDIM; ++g) S += sG[a][g] * wreg[g];
            float ev = emb[(long long)i * FDIM + t];
            float qq = q[i];
            comb_t[b1f + a * 8] = bf16bits(ev * S);
            comb_t[b2f + a * 8] = bf16bits(qq * S);
        }
    }

    // Phase C: fused M-contraction + vector_emb (k = 256+wave*16+lr).
    {
        int lane = t & 63, wave = t >> 6;
        int lr = lane & 15;
        int ko = (lane >> 4) * 8;
        int rbase = (lane >> 4) * 4;

        short8 af[8];
#pragma unroll
        for (int ks = 0; ks < 8; ++ks)
            af[ks] = *(const short8*)(&sE[lr][ks * 32 + ko]);

        float U0[4] = {}, U1[4] = {}, U2[4] = {};
#pragma unroll
        for (int g = 0; g < 16; ++g) {
            f32x4 acc = {0.f, 0.f, 0.f, 0.f};
            int nb = g * 4 + wave;   // n = g*64 + wave*16
            const short* Bb = aghTt + (long long)nb * 8 * 512 + lane * 8;
#pragma unroll
            for (int kb = 0; kb < 8; ++kb) {
                short8 b = *(const short8*)(Bb + kb * 512);
                acc = MFMA16(af[kb], b, acc);
            }
#pragma unroll
            for (int r = 0; r < 4; ++r) {
                int a = rbase + r;
                U0[r] += acc[r] * sGV[a][g];
                U1[r] += acc[r] * sGV[a][16 + g];
                U2[r] += acc[r] * sGV[a][32 + g];
            }
        }
        int off = wave * 16 + lr;           // k = 256 + off
        int kb = 8 + (off >> 5), kg = (off >> 3) & 3, ke = off & 7;
        long long bf = (((long long)mb * 18 + kb) * 4 + kg) * 128 + ke;
#pragma unroll
        for (int r = 0; r < 4; ++r) {
            int a = rbase + r;
            float v = sqrtf(U0[r] * U0[r] + U1[r] * U1[r] + U2[r] * U2[r]);
            comb_t[bf + a * 8] = bf16bits(v);
        }
    }
}

// ---------------------------------------------------------------------------
// Fused MLP v5: 32 atoms per 512-thr block (8 waves), grid 313 — covers all
// 256 CUs; LDS 33.8KB -> 2+ blocks/CU. All operand loads MFMA-native (one
// 1KB coalesced transaction per fragment). Phase 1 KB=18. Phase 3: 20
// col-frags, wave w -> {w, w+8, w+16(w<4)}. Last block: mb clamped on load,
// guarded on store.
// ---------------------------------------------------------------------------
__global__ __launch_bounds__(512) void mlp_fused(
        const short* __restrict__ comb_t,
        const short* __restrict__ W1t,
        const short* __restrict__ W2t,
        const short* __restrict__ W3t,
        const float* __restrict__ b1,
        const float* __restrict__ b2,
        const float* __restrict__ b3,
        float* __restrict__ outp) {
    __shared__ short h1s[32][264];
    __shared__ short h2s[32][264];
    int lane = threadIdx.x & 63;
    int wave = threadIdx.x >> 6;
    int m0 = blockIdx.x * 32;
    int mbb = blockIdx.x * 2;
    int lr = lane & 15;
    int ko = (lane >> 4) * 8;
    int rbase = (lane >> 4) * 4;

    const short* At[2];
#pragma unroll
    for (int fm = 0; fm < 2; ++fm) {
        int mb = mbb + fm;
        if (mb > 624) mb = 624;   // clamp; garbage rows discarded at store
        At[fm] = comb_t + (long long)mb * 18 * 512 + lane * 8;
    }

    // Phase 1: h1 = gelu(comb @ W1^T + b1); wave cols [32w, 32w+32), KB=18
    {
        f32x4 acc[2][2] = {};
        const short* Bt = W1t + (long long)(wave * 2) * 18 * 512 + lane * 8;
#pragma unroll 3
        for (int kbi = 0; kbi < 18; ++kbi) {
            short8 a[2], b[2];
#pragma unroll
            for (int fm = 0; fm < 2; ++fm) a[fm] = *(const short8*)(At[fm] + kbi * 512);
#pragma unroll
            for (int fn = 0; fn < 2; ++fn)
                b[fn] = *(const short8*)(Bt + fn * 18 * 512 + kbi * 512);
#pragma unroll
            for (int fm = 0; fm < 2; ++fm)
#pragma unroll
                for (int fn = 0; fn < 2; ++fn)
                    acc[fm][fn] = MFMA16(a[fm], b[fn], acc[fm][fn]);
        }
#pragma unroll
        for (int fn = 0; fn < 2; ++fn) {
            int col = wave * 32 + fn * 16 + lr;
            float bias = b1[col];
#pragma unroll
            for (int fm = 0; fm < 2; ++fm)
#pragma unroll
                for (int r = 0; r < 4; ++r)
                    h1s[fm * 16 + rbase + r][col] = bf16bits(gelu_exact(acc[fm][fn][r] + bias));
        }
    }
    __syncthreads();

    // Phase 2: h2 = gelu(h1 @ W2^T + b2); A from LDS, B native (KB=8)
    {
        f32x4 acc[2][2] = {};
        const short* Bt = W2t + (long long)(wave * 2) * 8 * 512 + lane * 8;
#pragma unroll
        for (int kbi = 0; kbi < 8; ++kbi) {
            short8 a[2], b[2];
#pragma unroll
            for (int fm = 0; fm < 2; ++fm)
                a[fm] = *(const short8*)(&h1s[fm * 16 + lr][ko + kbi * 32]);
#pragma unroll
            for (int fn = 0; fn < 2; ++fn)
                b[fn] = *(const short8*)(Bt + fn * 8 * 512 + kbi * 512);
#pragma unroll
            for (int fm = 0; fm < 2; ++fm)
#pragma unroll
                for (int fn = 0; fn < 2; ++fn)
                    acc[fm][fn] = MFMA16(a[fm], b[fn], acc[fm][fn]);
        }
#pragma unroll
        for (int fn = 0; fn < 2; ++fn) {
            int col = wave * 32 + fn * 16 + lr;
            float bias = b2[col];
#pragma unroll
            for (int fm = 0; fm < 2; ++fm)
#pragma unroll
                for (int r = 0; r < 4; ++r)
                    h2s[fm * 16 + rbase + r][col] = bf16bits(gelu_exact(acc[fm][fn][r] + bias));
        }
    }
    __syncthreads();

    // Phase 3: out = h2 @ W3^T + b3 (320 padded cols = 20 frags, KB=8)
    {
        int f0 = wave, f1 = wave + 8, f2 = wave + 16;
        bool has2 = (wave < 4);
        f32x4 acc0[2] = {}, acc1[2] = {}, acc2[2] = {};
        const short* B0 = W3t + (long long)f0 * 8 * 512 + lane * 8;
        const short* B1 = W3t + (long long)f1 * 8 * 512 + lane * 8;
        const short* B2 = W3t + (long long)(has2 ? f2 : f0) * 8 * 512 + lane * 8;
#pragma unroll
        for (int kbi = 0; kbi < 8; ++kbi) {
            short8 a[2];
#pragma unroll
            for (int fm = 0; fm < 2; ++fm)
                a[fm] = *(const short8*)(&h2s[fm * 16 + lr][ko + kbi * 32]);
            short8 b0 = *(const short8*)(B0 + kbi * 512);
            short8 b1v = *(const short8*)(B1 + kbi * 512);
#pragma unroll
            for (int fm = 0; fm < 2; ++fm) {
                acc0[fm] = MFMA16(a[fm], b0, acc0[fm]);
                acc1[fm] = MFMA16(a[fm], b1v, acc1[fm]);
            }
            if (has2) {
                short8 b2v = *(const short8*)(B2 + kbi * 512);
#pragma unroll
                for (int fm = 0; fm < 2; ++fm)
                    acc2[fm] = MFMA16(a[fm], b2v, acc2[fm]);
            }
        }
#pragma unroll
        for (int slot = 0; slot < 3; ++slot) {
            if (slot == 2 && !has2) continue;
            int f = (slot == 0) ? f0 : (slot == 1) ? f1 : f2;
            int col = f * 16 + lr;
            if (col >= MLP_OUT) continue;
            float bias = b3[col];
#pragma unroll
            for (int fm = 0; fm < 2; ++fm) {
#pragma unroll
                for (int r = 0; r < 4; ++r) {
                    int row = m0 + fm * 16 + rbase + r;
                    if (row >= N_ATOMS) continue;
                    f32x4 av = (slot == 0) ? acc0[fm] : (slot == 1) ? acc1[fm] : acc2[fm];
                    float v = av[r] + bias;
                    if (col == 0)      outp[2560000 + row] = v;
                    else if (col == 1) outp[2570000 + row] = v;
                    else               outp[(long long)row * 256 + (col - 2)] = v;
                }
            }
        }
    }
}

extern "C" void kernel_launch(void* const* d_in, const int* in_sizes, int n_in,
                              void* d_out, int out_size, void* d_ws, size_t ws_size,
                              hipStream_t stream) {
    const float* emb  = (const float*)d_in[0];
    const float* q    = (const float*)d_in[1];
    const int*   pidx = (const int*)d_in[2];
    const float* gs   = (const float*)d_in[3];
    const float* gv   = (const float*)d_in[4];
    const float* agh  = (const float*)d_in[5];
    const float* W_gs = (const float*)d_in[6];
    const float* W1   = (const float*)d_in[7];
    const float* b1   = (const float*)d_in[8];
    const float* W2   = (const float*)d_in[9];
    const float* b2   = (const float*)d_in[10];
    const float* W3   = (const float*)d_in[11];
    const float* b3   = (const float*)d_in[12];
    float* out = (float*)d_out;
    float* ws  = (float*)d_ws;

    // Workspace (float-slot offsets). Peak 8,308,528 floats = 33.2 MB
    // (42.9 MB proven safe in r5).
    int*   cnt    = (int*)(ws);                       // 10,000
    int*   startA = (int*)(ws + 10000);               // 10,000
    int*   cursor = (int*)(ws + 20000);               // 10,000
    __hip_bfloat16* prS = (__hip_bfloat16*)(ws + 30000);  // 160000x64 bf16 (5,120,000 f)
    short* aghTt = (short*)(ws + 5150000);            // 262,144 elems (131,072 f)
    short* W1t   = (short*)(ws + 5281072);            // 147,456 elems (73,728 f)
    short* W2t   = (short*)(ws + 5354800);            // 65,536 elems (32,768 f)
    short* W3t   = (short*)(ws + 5387568);            // 81,920 elems (40,960 f)
    short* comb_t= (short*)(ws + 5428528);            // 5,760,000 elems (2,880,000 f)
    // end: 8,308,528 floats

    const int* idx_j = pidx + N_PAIRS;

    {   // weight conversions into MFMA-native layout + cnt zeroing
        int blocks = (PREP_TOTAL + 255) / 256;
        prep_kernel<<<blocks, 256, 0, stream>>>(W1, W2, agh, W3,
                                                W1t, W2t, aghTt, W3t, cnt);
    }
    {   // count-sort pairs by atom + materialize sort-ordered bf16 pair rows
        int blocks = (N_PAIRS + 255) / 256;
        hist_kernel<<<blocks, 256, 0, stream>>>(idx_j, cnt);
        scan_kernel<<<1, 1024, 0, stream>>>(cnt, startA, cursor);
        scatter_data_kernel<<<blocks, 256, 0, stream>>>(idx_j, cursor, gs, gv, prS);
    }
    // streaming gather + M-contraction + combined-builder (625 blocks)
    gatherM_build<<<625, 256, 0, stream>>>(
        prS, startA, cnt, emb, q, W_gs, aghTt, comb_t);
    // fused 3-layer MLP + output remap (313 blocks x 512 thr)
    mlp_fused<<<(N_ATOMS + 31) / 32, 512, 0, stream>>>(
        comb_t, W1t, W2t, W3t, b1, b2, b3, out);
}